// Round 1
// baseline (800.059 us; speedup 1.0000x reference)
//
#include <hip/hip_runtime.h>
#include <math.h>

// ---------------------------------------------------------------------------
// SLAY sampled-softmax loss on MI355X.
// H=4 heads, D=128, P=16 anchors, M=32 features, R=2 quad nodes, E=512.
// B=512, S=64, K=5, L=32768 labels, VOCAB=100000.
//
// Decomposition (never materialize phi matrices):
//   phi[n,(r,h,p,m)] = poly[n,h,p] * prf[r,n,h,m]
//   Z[r,h,p,m]  = sum_l poly_W[l,h,p]*prf_W[r,l,h,m]   (per-block LDS matmul + atomics)
//   denom[b]    = sum_f phi_q[b,f]*Z[f]
//   nums[b,k]   = sum_h (poly_W.poly_q)[h] * sum_r (prf_W.prf_q)[r,h]   (factorized!)
// ---------------------------------------------------------------------------

namespace {
constexpr double Cq  = 2.0 + 1e-6;
constexpr double QN0 = 0.5857864376269049  / Cq;   // laggauss(2) nodes / C
constexpr double QN1 = 3.414213562373095   / Cq;
constexpr double QW0 = 0.8535533905932738  / Cq;   // laggauss(2) weights / C
constexpr double QW1 = 0.14644660940672624 / Cq;

// workspace float offsets
constexpr size_t OFF_QUERY = 0;                    // 512*512
constexpr size_t OFF_POLYQ = 262144;               // 512*4*16   [b][h][p]
constexpr size_t OFF_PRFQ  = OFF_POLYQ + 32768;    // 512*2*4*32 [b][r][h][m]
constexpr size_t OFF_Z     = OFF_PRFQ + 131072;    // 4096       [r][h][p][m]
constexpr size_t OFF_LOGZ  = OFF_Z + 4096;         // 512
constexpr size_t OFF_ANCT  = OFF_LOGZ + 512;       // 128*16 anchors transposed [d][p]
}

// Single-pass raw accumulation: sumsq + 16 poly dots + 64 prf dots over d=0..127.
// All coefficient loads are wave-uniform (h,d uniform) -> scalar/broadcast loads.
__device__ __forceinline__ void accum_feat(const float* __restrict__ x, long xstride,
                                           const float* __restrict__ anct,
                                           const float* __restrict__ omega, int h,
                                           float& sumsq, float poly[16], float prf[64])
{
    for (int d = 0; d < 128; ++d) {
        float xv = x[(long)d * xstride];
        sumsq = fmaf(xv, xv, sumsq);
        const float4* a4 = (const float4*)(anct + d * 16);
#pragma unroll
        for (int j = 0; j < 4; ++j) {
            float4 a = a4[j];
            poly[4*j+0] = fmaf(xv, a.x, poly[4*j+0]);
            poly[4*j+1] = fmaf(xv, a.y, poly[4*j+1]);
            poly[4*j+2] = fmaf(xv, a.z, poly[4*j+2]);
            poly[4*j+3] = fmaf(xv, a.w, poly[4*j+3]);
        }
#pragma unroll
        for (int r = 0; r < 2; ++r) {
            const float4* w4 = (const float4*)(omega + (((r*4 + h)*128 + d) * 32));
#pragma unroll
            for (int j = 0; j < 8; ++j) {
                float4 w = w4[j];
                prf[r*32 + 4*j+0] = fmaf(xv, w.x, prf[r*32 + 4*j+0]);
                prf[r*32 + 4*j+1] = fmaf(xv, w.y, prf[r*32 + 4*j+1]);
                prf[r*32 + 4*j+2] = fmaf(xv, w.z, prf[r*32 + 4*j+2]);
                prf[r*32 + 4*j+3] = fmaf(xv, w.w, prf[r*32 + 4*j+3]);
            }
        }
    }
}

// Apply normalization, square/scale poly, exp/scale prf. In-place.
__device__ __forceinline__ void finalize_feat(float sumsq, float poly[16], float prf[64])
{
    float rn = 1.0f / fmaxf(sqrtf(sumsq), 1e-6f);
#pragma unroll
    for (int p = 0; p < 16; ++p) { float v = poly[p] * rn; poly[p] = v * v * 0.25f; }
    const float s0 = (float)QN0, s1 = (float)QN1;
    const float g0 = sqrtf(2.0f * (float)QN0), g1 = sqrtf(2.0f * (float)QN1);
    const float c0 = sqrtf((float)QW0) * 0.17677669529663687f;  // sqrt(w0)/sqrt(M)
    const float c1 = sqrtf((float)QW1) * 0.17677669529663687f;
#pragma unroll
    for (int m = 0; m < 32; ++m) {
        float z0 = prf[m]      * rn * g0 - s0;
        float z1 = prf[32 + m] * rn * g1 - s1;
        z0 = fminf(fmaxf(z0, -10.f), 10.f);
        z1 = fminf(fmaxf(z1, -10.f), 10.f);
        prf[m]      = expf(z0) * c0;
        prf[32 + m] = expf(z1) * c1;
    }
}

// anchors [16][128] -> anchorsT [128][16] so per-d coef loads are contiguous
__global__ void k_tr_anchors(const float* __restrict__ anchors, float* __restrict__ anct)
{
    for (int i = threadIdx.x; i < 16 * 128; i += 256) {
        int p = i & 15, d = i >> 4;
        anct[i] = anchors[p * 128 + d];
    }
}

// masked mean embedding: one block per batch row
__global__ void k_mean_embed(const int* __restrict__ idx, const float* __restrict__ mask,
                             const float* __restrict__ emb, float* __restrict__ query)
{
    int b = blockIdx.x, t = threadIdx.x;
    float2 acc = make_float2(0.f, 0.f);
    float msum = 0.f;
    for (int s = 0; s < 64; ++s) {
        float mv = mask[b * 64 + s];
        msum += mv;
        const float2* row = (const float2*)(emb + (size_t)idx[b * 64 + s] * 512);
        float2 v = row[t];
        acc.x = fmaf(mv, v.x, acc.x);
        acc.y = fmaf(mv, v.y, acc.y);
    }
    float inv = 1.0f / fmaxf(msum, 1e-9f);
    ((float2*)(query + (size_t)b * 512))[t] = make_float2(acc.x * inv, acc.y * inv);
}

// features for the 512 query rows; wave w of each block handles head w (uniform coefs)
__global__ void k_query_feat(const float* __restrict__ query, const float* __restrict__ anct,
                             const float* __restrict__ omega, float* __restrict__ polyq,
                             float* __restrict__ prfq)
{
    int t = threadIdx.x;
    int h = t >> 6;
    int b = blockIdx.x * 64 + (t & 63);
    float sumsq = 0.f, poly[16] = {}, prf[64] = {};
    accum_feat(query + (size_t)b * 512 + h * 128, 1, anct, omega, h, sumsq, poly, prf);
    finalize_feat(sumsq, poly, prf);
#pragma unroll
    for (int p = 0; p < 16; ++p) polyq[(b * 4 + h) * 16 + p] = poly[p];
#pragma unroll
    for (int r = 0; r < 2; ++r)
#pragma unroll
        for (int m = 0; m < 32; ++m)
            prfq[((b * 2 + r) * 4 + h) * 32 + m] = prf[r * 32 + m];
}

// dominant kernel: features for all 32768 labels + block-local Z matmul + atomics.
// block = 256 labels x 1 head; thread t -> label l0+t. ck column reads coalesce
// perfectly (lane i reads ck[e*32768 + l0 + i]).
__global__ void __launch_bounds__(256) k_labels(const float* __restrict__ ck,
                                                const float* __restrict__ anct,
                                                const float* __restrict__ omega,
                                                float* __restrict__ Z)
{
    __shared__ float polyS[128 * 17];               // stride 17: conflict-free
    __shared__ __align__(16) float prfS[128 * 68];  // stride 68: float4-aligned
    int t = threadIdx.x;
    int h = blockIdx.x & 3;
    int l = (blockIdx.x >> 2) * 256 + t;

    float sumsq = 0.f, poly[16] = {}, prf[64] = {};
    accum_feat(ck + (size_t)h * 128 * 32768 + l, 32768, anct, omega, h, sumsq, poly, prf);
    finalize_feat(sumsq, poly, prf);

    // mini-matmul Z[r,p,m] += sum_l poly[l,p]*prf[l,r,m], two batches of 128 labels
    int zr = t >> 7, zp = (t >> 3) & 15, zm4 = t & 7;  // thread owns Z[zr][zp][4m's]
    float4 zacc = make_float4(0.f, 0.f, 0.f, 0.f);
#pragma unroll
    for (int bi = 0; bi < 2; ++bi) {
        if ((t >> 7) == bi) {
            int tl = t & 127;
#pragma unroll
            for (int p = 0; p < 16; ++p) polyS[tl * 17 + p] = poly[p];
            float4* dst = (float4*)(prfS + tl * 68);
#pragma unroll
            for (int j = 0; j < 16; ++j)
                dst[j] = make_float4(prf[4*j], prf[4*j+1], prf[4*j+2], prf[4*j+3]);
        }
        __syncthreads();
        for (int q = 0; q < 128; ++q) {
            float  pv = polyS[q * 17 + zp];
            float4 fv = *(const float4*)(prfS + q * 68 + zr * 32 + zm4 * 4);
            zacc.x = fmaf(pv, fv.x, zacc.x);
            zacc.y = fmaf(pv, fv.y, zacc.y);
            zacc.z = fmaf(pv, fv.z, zacc.z);
            zacc.w = fmaf(pv, fv.w, zacc.w);
        }
        __syncthreads();
    }
    float* zdst = Z + ((zr * 4 + h) * 16 + zp) * 32 + zm4 * 4;
    atomicAdd(zdst + 0, zacc.x);
    atomicAdd(zdst + 1, zacc.y);
    atomicAdd(zdst + 2, zacc.z);
    atomicAdd(zdst + 3, zacc.w);
}

// denom[b] = phi_q[b].Z + 1e-6 ; one wave per b
__global__ void k_denom(const float* __restrict__ polyq, const float* __restrict__ prfq,
                        const float* __restrict__ Z, float* __restrict__ logZ)
{
    int t = threadIdx.x;
    int lane = t & 63;
    int b = blockIdx.x * 4 + (t >> 6);
    float acc = 0.f;
    for (int i = 0; i < 64; ++i) {
        int f = i * 64 + lane;                         // coalesced Z reads
        int m = f & 31, p = (f >> 5) & 15, hh = (f >> 9) & 3, r = f >> 11;
        float phi = polyq[(b * 4 + hh) * 16 + p] * prfq[((b * 2 + r) * 4 + hh) * 32 + m];
        acc = fmaf(phi, Z[f], acc);
    }
#pragma unroll
    for (int o = 1; o < 64; o <<= 1) acc += __shfl_xor(acc, o, 64);
    if (lane == 0) logZ[b] = logf(acc + 1e-6f);
}

// loss: thread = (b,k,h); recompute label-row features; factorized dot; 4-lane reduce
__global__ void k_loss(const float* __restrict__ ck, const float* __restrict__ anct,
                       const float* __restrict__ omega, const int* __restrict__ labels,
                       const float* __restrict__ lmask, const float* __restrict__ polyq,
                       const float* __restrict__ prfq, const float* __restrict__ logZ,
                       float* __restrict__ out)
{
    int g = blockIdx.x * 256 + threadIdx.x;
    if (g >= 512 * 5 * 4) return;
    int h = g & 3, bk = g >> 2;
    int k = bk % 5, b = bk / 5;
    int l = max(labels[b * 5 + k], 0);

    float sumsq = 0.f, poly[16] = {}, prf[64] = {};
    accum_feat(ck + (size_t)h * 128 * 32768 + l, 32768, anct, omega, h, sumsq, poly, prf);
    finalize_feat(sumsq, poly, prf);

    float pd = 0.f;
#pragma unroll
    for (int p = 0; p < 16; ++p) pd = fmaf(poly[p], polyq[(b * 4 + h) * 16 + p], pd);
    float f0 = 0.f, f1 = 0.f;
#pragma unroll
    for (int m = 0; m < 32; ++m) {
        f0 = fmaf(prf[m],      prfq[((b * 2 + 0) * 4 + h) * 32 + m], f0);
        f1 = fmaf(prf[32 + m], prfq[((b * 2 + 1) * 4 + h) * 32 + m], f1);
    }
    float c = pd * (f0 + f1);
    c += __shfl_xor(c, 1, 64);   // sum over the 4 heads (lanes h=0..3 adjacent)
    c += __shfl_xor(c, 2, 64);
    if (h == 0) {
        float val = (logf(c + 1e-6f) - logZ[b]) * lmask[b * 5 + k];
        atomicAdd(out, val * (-1.0f / 512.0f));
    }
}

extern "C" void kernel_launch(void* const* d_in, const int* in_sizes, int n_in,
                              void* d_out, int out_size, void* d_ws, size_t ws_size,
                              hipStream_t stream)
{
    const int*   indices = (const int*)  d_in[0];
    const float* mask    = (const float*)d_in[1];
    const int*   labels  = (const int*)  d_in[2];
    const float* lmask   = (const float*)d_in[3];
    const float* emb     = (const float*)d_in[4];
    const float* ck      = (const float*)d_in[5];   // [512][32768]
    const float* omega   = (const float*)d_in[6];   // [2][4][128][32]
    const float* anchors = (const float*)d_in[7];   // [16][128]
    float* ws  = (float*)d_ws;
    float* out = (float*)d_out;

    hipMemsetAsync(ws + OFF_Z, 0, 4096 * sizeof(float), stream);
    hipMemsetAsync(out, 0, sizeof(float), stream);

    k_tr_anchors<<<1, 256, 0, stream>>>(anchors, ws + OFF_ANCT);
    k_mean_embed<<<512, 256, 0, stream>>>(indices, mask, emb, ws + OFF_QUERY);
    k_query_feat<<<8, 256, 0, stream>>>(ws + OFF_QUERY, ws + OFF_ANCT, omega,
                                        ws + OFF_POLYQ, ws + OFF_PRFQ);
    k_labels<<<512, 256, 0, stream>>>(ck, ws + OFF_ANCT, omega, ws + OFF_Z);
    k_denom<<<128, 256, 0, stream>>>(ws + OFF_POLYQ, ws + OFF_PRFQ, ws + OFF_Z,
                                     ws + OFF_LOGZ);
    k_loss<<<40, 256, 0, stream>>>(ck, ws + OFF_ANCT, omega, labels, lmask,
                                   ws + OFF_POLYQ, ws + OFF_PRFQ, ws + OFF_LOGZ, out);
}

// Round 2
// 414.928 us; speedup vs baseline: 1.9282x; 1.9282x over previous
//
#include <hip/hip_runtime.h>
#include <math.h>

// ---------------------------------------------------------------------------
// SLAY sampled-softmax loss on MI355X.
// H=4 heads, D=128, P=16 anchors, M=32 features, R=2 quad nodes, E=512.
// B=512, S=64, K=5, L=32768 labels, VOCAB=100000.
//
// Decomposition (never materialize phi matrices):
//   phi[n,(r,h,p,m)] = poly[n,h,p] * prf[r,n,h,m]
//   Z[r,h,p,m]  = sum_l poly_W[l,h,p]*prf_W[r,l,h,m]   (per-block LDS matmul + atomics)
//   denom[b]    = sum_f phi_q[b,f]*Z[f]
//   nums[b,k]   = sum_h (poly_W.poly_q)[h] * sum_r (prf_W.prf_q)[r,h]   (factorized)
//
// R1 change: k_labels writes compact feature rows for the ~2560 labels that
// appear in `labels` (slot table), so k_loss is a 3 MB gather instead of a
// 72 MB strided ck scatter. k_query_feat re-parallelized to 512 blocks.
// ---------------------------------------------------------------------------

namespace {
constexpr double Cq  = 2.0 + 1e-6;
constexpr double QN0 = 0.5857864376269049  / Cq;   // laggauss(2) nodes / C
constexpr double QN1 = 3.414213562373095   / Cq;
constexpr double QW0 = 0.8535533905932738  / Cq;   // laggauss(2) weights / C
constexpr double QW1 = 0.14644660940672624 / Cq;

// workspace float offsets
constexpr size_t OFF_QUERY = 0;                    // 512*512
constexpr size_t OFF_POLYQ = 262144;               // 512*4*16   [b][h][p]
constexpr size_t OFF_PRFQ  = OFF_POLYQ + 32768;    // 512*2*4*32 [b][r][h][m]
constexpr size_t OFF_Z     = OFF_PRFQ + 131072;    // 4096       [r][h][p][m]
constexpr size_t OFF_LOGZ  = OFF_Z + 4096;         // 512
constexpr size_t OFF_ANCT  = OFF_LOGZ + 512;       // 128*16 anchors transposed [d][p]
constexpr size_t OFF_SLOT  = OFF_ANCT + 2048;      // 32768 ints: label -> slot or -1
constexpr size_t OFF_FEAT  = OFF_SLOT + 32768;     // 2560*4*80  [slot][h][16 poly + 64 prf]
}

// Single-pass raw accumulation: sumsq + 16 poly dots + 64 prf dots over d=0..127.
// All coefficient loads are wave-uniform (h,d uniform) -> scalar/broadcast loads.
__device__ __forceinline__ void accum_feat(const float* __restrict__ x, long xstride,
                                           const float* __restrict__ anct,
                                           const float* __restrict__ omega, int h,
                                           float& sumsq, float poly[16], float prf[64])
{
    for (int d = 0; d < 128; ++d) {
        float xv = x[(long)d * xstride];
        sumsq = fmaf(xv, xv, sumsq);
        const float4* a4 = (const float4*)(anct + d * 16);
#pragma unroll
        for (int j = 0; j < 4; ++j) {
            float4 a = a4[j];
            poly[4*j+0] = fmaf(xv, a.x, poly[4*j+0]);
            poly[4*j+1] = fmaf(xv, a.y, poly[4*j+1]);
            poly[4*j+2] = fmaf(xv, a.z, poly[4*j+2]);
            poly[4*j+3] = fmaf(xv, a.w, poly[4*j+3]);
        }
#pragma unroll
        for (int r = 0; r < 2; ++r) {
            const float4* w4 = (const float4*)(omega + (((r*4 + h)*128 + d) * 32));
#pragma unroll
            for (int j = 0; j < 8; ++j) {
                float4 w = w4[j];
                prf[r*32 + 4*j+0] = fmaf(xv, w.x, prf[r*32 + 4*j+0]);
                prf[r*32 + 4*j+1] = fmaf(xv, w.y, prf[r*32 + 4*j+1]);
                prf[r*32 + 4*j+2] = fmaf(xv, w.z, prf[r*32 + 4*j+2]);
                prf[r*32 + 4*j+3] = fmaf(xv, w.w, prf[r*32 + 4*j+3]);
            }
        }
    }
}

// Apply normalization, square/scale poly, exp/scale prf. In-place.
__device__ __forceinline__ void finalize_feat(float sumsq, float poly[16], float prf[64])
{
    float rn = 1.0f / fmaxf(sqrtf(sumsq), 1e-6f);
#pragma unroll
    for (int p = 0; p < 16; ++p) { float v = poly[p] * rn; poly[p] = v * v * 0.25f; }
    const float s0 = (float)QN0, s1 = (float)QN1;
    const float g0 = sqrtf(2.0f * (float)QN0), g1 = sqrtf(2.0f * (float)QN1);
    const float c0 = sqrtf((float)QW0) * 0.17677669529663687f;  // sqrt(w0)/sqrt(M)
    const float c1 = sqrtf((float)QW1) * 0.17677669529663687f;
#pragma unroll
    for (int m = 0; m < 32; ++m) {
        float z0 = prf[m]      * rn * g0 - s0;
        float z1 = prf[32 + m] * rn * g1 - s1;
        z0 = fminf(fmaxf(z0, -10.f), 10.f);
        z1 = fminf(fmaxf(z1, -10.f), 10.f);
        prf[m]      = expf(z0) * c0;
        prf[32 + m] = expf(z1) * c1;
    }
}

// anchors [16][128] -> anchorsT [128][16] so per-d coef loads are contiguous
__global__ void k_tr_anchors(const float* __restrict__ anchors, float* __restrict__ anct)
{
    for (int i = threadIdx.x; i < 16 * 128; i += 256) {
        int p = i & 15, d = i >> 4;
        anct[i] = anchors[p * 128 + d];
    }
}

// slot[label] = (b,k) flat index (any winner among duplicates is fine)
__global__ void k_scatter_slots(const int* __restrict__ labels, int* __restrict__ slot)
{
    int i = blockIdx.x * 256 + threadIdx.x;
    if (i < 512 * 5) slot[max(labels[i], 0)] = i;
}

// masked mean embedding: one block per batch row
__global__ void k_mean_embed(const int* __restrict__ idx, const float* __restrict__ mask,
                             const float* __restrict__ emb, float* __restrict__ query)
{
    int b = blockIdx.x, t = threadIdx.x;
    float2 acc = make_float2(0.f, 0.f);
    float msum = 0.f;
    for (int s = 0; s < 64; ++s) {
        float mv = mask[b * 64 + s];
        msum += mv;
        const float2* row = (const float2*)(emb + (size_t)idx[b * 64 + s] * 512);
        float2 v = row[t];
        acc.x = fmaf(mv, v.x, acc.x);
        acc.y = fmaf(mv, v.y, acc.y);
    }
    float inv = 1.0f / fmaxf(msum, 1e-9f);
    ((float2*)(query + (size_t)b * 512))[t] = make_float2(acc.x * inv, acc.y * inv);
}

// query features: one block per batch row b; x staged in LDS; one dot/thread.
// tasks per b: 4 heads x (16 poly + 64 prf) = 320; threads 0..63 take a 2nd task.
__global__ void k_query_feat(const float* __restrict__ query, const float* __restrict__ anct,
                             const float* __restrict__ omega, float* __restrict__ polyq,
                             float* __restrict__ prfq)
{
    __shared__ float xs[512];
    __shared__ float rnS[4];
    int b = blockIdx.x, t = threadIdx.x;
    xs[t]       = query[(size_t)b * 512 + t];
    xs[t + 256] = query[(size_t)b * 512 + 256 + t];
    __syncthreads();
    int w = t >> 6, lane = t & 63;
    if (w == 0 || w == 1 || w == 2 || w == 3) {
        float v0 = xs[w * 128 + lane], v1 = xs[w * 128 + 64 + lane];
        float ss = fmaf(v0, v0, v1 * v1);
#pragma unroll
        for (int o = 1; o < 64; o <<= 1) ss += __shfl_xor(ss, o, 64);
        if (lane == 0) rnS[w] = 1.0f / fmaxf(sqrtf(ss), 1e-6f);
    }
    __syncthreads();

    const float s_[2] = {(float)QN0, (float)QN1};
    const float g_[2] = {sqrtf(2.0f * (float)QN0), sqrtf(2.0f * (float)QN1)};
    const float c_[2] = {sqrtf((float)QW0) * 0.17677669529663687f,
                         sqrtf((float)QW1) * 0.17677669529663687f};

    for (int tau = t; tau < 320; tau += 256) {
        int h = tau / 80, j = tau - h * 80;
        const float* xh = xs + h * 128;
        float acc = 0.f;
        if (j < 16) {
            for (int d = 0; d < 128; ++d) acc = fmaf(xh[d], anct[d * 16 + j], acc);
            float v = acc * rnS[h];
            polyq[(b * 4 + h) * 16 + j] = v * v * 0.25f;
        } else {
            int rj = j - 16, r = rj >> 5, m = rj & 31;
            const float* om = omega + ((size_t)(r * 4 + h) * 128) * 32 + m;
            for (int d = 0; d < 128; ++d) acc = fmaf(xh[d], om[d * 32], acc);
            float z = acc * rnS[h] * g_[r] - s_[r];
            z = fminf(fmaxf(z, -10.f), 10.f);
            prfq[((b * 2 + r) * 4 + h) * 32 + m] = expf(z) * c_[r];
        }
    }
}

// dominant kernel: features for all 32768 labels + block-local Z matmul + atomics
// + selective compact feature write for labels present in the batch.
// block = 256 labels x 1 head; thread t -> label l0+t. ck column reads coalesce
// perfectly (lane i reads ck[e*32768 + l0 + i]).
__global__ void __launch_bounds__(256) k_labels(const float* __restrict__ ck,
                                                const float* __restrict__ anct,
                                                const float* __restrict__ omega,
                                                const int* __restrict__ slot,
                                                float* __restrict__ feat,
                                                float* __restrict__ Z)
{
    __shared__ float polyS[128 * 17];               // stride 17: conflict-free
    __shared__ __align__(16) float prfS[128 * 68];  // stride 68: float4-aligned
    int t = threadIdx.x;
    int h = blockIdx.x & 3;
    int l = (blockIdx.x >> 2) * 256 + t;

    float sumsq = 0.f, poly[16] = {}, prf[64] = {};
    accum_feat(ck + (size_t)h * 128 * 32768 + l, 32768, anct, omega, h, sumsq, poly, prf);
    finalize_feat(sumsq, poly, prf);

    // selective compact store for the batch's positive labels
    int s = slot[l];
    if (s >= 0) {
        float4* dst = (float4*)(feat + ((size_t)s * 4 + h) * 80);
#pragma unroll
        for (int j = 0; j < 4; ++j)
            dst[j] = make_float4(poly[4*j], poly[4*j+1], poly[4*j+2], poly[4*j+3]);
#pragma unroll
        for (int j = 0; j < 16; ++j)
            dst[4 + j] = make_float4(prf[4*j], prf[4*j+1], prf[4*j+2], prf[4*j+3]);
    }

    // mini-matmul Z[r,p,m] += sum_l poly[l,p]*prf[l,r,m], two batches of 128 labels
    int zr = t >> 7, zp = (t >> 3) & 15, zm4 = t & 7;  // thread owns Z[zr][zp][4m's]
    float4 zacc = make_float4(0.f, 0.f, 0.f, 0.f);
#pragma unroll
    for (int bi = 0; bi < 2; ++bi) {
        if ((t >> 7) == bi) {
            int tl = t & 127;
#pragma unroll
            for (int p = 0; p < 16; ++p) polyS[tl * 17 + p] = poly[p];
            float4* dst = (float4*)(prfS + tl * 68);
#pragma unroll
            for (int j = 0; j < 16; ++j)
                dst[j] = make_float4(prf[4*j], prf[4*j+1], prf[4*j+2], prf[4*j+3]);
        }
        __syncthreads();
        for (int q = 0; q < 128; ++q) {
            float  pv = polyS[q * 17 + zp];
            float4 fv = *(const float4*)(prfS + q * 68 + zr * 32 + zm4 * 4);
            zacc.x = fmaf(pv, fv.x, zacc.x);
            zacc.y = fmaf(pv, fv.y, zacc.y);
            zacc.z = fmaf(pv, fv.z, zacc.z);
            zacc.w = fmaf(pv, fv.w, zacc.w);
        }
        __syncthreads();
    }
    float* zdst = Z + ((zr * 4 + h) * 16 + zp) * 32 + zm4 * 4;
    atomicAdd(zdst + 0, zacc.x);
    atomicAdd(zdst + 1, zacc.y);
    atomicAdd(zdst + 2, zacc.z);
    atomicAdd(zdst + 3, zacc.w);
}

// denom[b] = phi_q[b].Z + 1e-6 ; one wave per b
__global__ void k_denom(const float* __restrict__ polyq, const float* __restrict__ prfq,
                        const float* __restrict__ Z, float* __restrict__ logZ)
{
    int t = threadIdx.x;
    int lane = t & 63;
    int b = blockIdx.x * 4 + (t >> 6);
    float acc = 0.f;
    for (int i = 0; i < 64; ++i) {
        int f = i * 64 + lane;                         // coalesced Z reads
        int m = f & 31, p = (f >> 5) & 15, hh = (f >> 9) & 3, r = f >> 11;
        float phi = polyq[(b * 4 + hh) * 16 + p] * prfq[((b * 2 + r) * 4 + hh) * 32 + m];
        acc = fmaf(phi, Z[f], acc);
    }
#pragma unroll
    for (int o = 1; o < 64; o <<= 1) acc += __shfl_xor(acc, o, 64);
    if (lane == 0) logZ[b] = logf(acc + 1e-6f);
}

// loss: thread = (b,k,h); gather stored label features; factorized dot; quad reduce
__global__ void k_loss(const int* __restrict__ labels, const float* __restrict__ lmask,
                       const int* __restrict__ slot, const float* __restrict__ feat,
                       const float* __restrict__ polyq, const float* __restrict__ prfq,
                       const float* __restrict__ logZ, float* __restrict__ out)
{
    int g = blockIdx.x * 256 + threadIdx.x;
    if (g >= 512 * 5 * 4) return;
    int h = g & 3, bk = g >> 2;
    int k = bk % 5, b = bk / 5;
    int l = max(labels[b * 5 + k], 0);
    int s = slot[l];

    const float4* f4 = (const float4*)(feat + ((size_t)s * 4 + h) * 80);
    const float* pq = polyq + (b * 4 + h) * 16;
    const float* q0 = prfq + ((b * 2 + 0) * 4 + h) * 32;
    const float* q1 = prfq + ((b * 2 + 1) * 4 + h) * 32;

    float pd = 0.f;
#pragma unroll
    for (int j = 0; j < 4; ++j) {
        float4 fp = f4[j];
        pd = fmaf(fp.x, pq[4*j+0], pd);
        pd = fmaf(fp.y, pq[4*j+1], pd);
        pd = fmaf(fp.z, pq[4*j+2], pd);
        pd = fmaf(fp.w, pq[4*j+3], pd);
    }
    float f0 = 0.f, f1 = 0.f;
#pragma unroll
    for (int j = 0; j < 8; ++j) {
        float4 fv = f4[4 + j];
        f0 = fmaf(fv.x, q0[4*j+0], f0);
        f0 = fmaf(fv.y, q0[4*j+1], f0);
        f0 = fmaf(fv.z, q0[4*j+2], f0);
        f0 = fmaf(fv.w, q0[4*j+3], f0);
        float4 fw = f4[12 + j];
        f1 = fmaf(fw.x, q1[4*j+0], f1);
        f1 = fmaf(fw.y, q1[4*j+1], f1);
        f1 = fmaf(fw.z, q1[4*j+2], f1);
        f1 = fmaf(fw.w, q1[4*j+3], f1);
    }
    float c = pd * (f0 + f1);
    c += __shfl_xor(c, 1, 64);   // sum over the 4 heads (lanes h=0..3 adjacent)
    c += __shfl_xor(c, 2, 64);
    if (h == 0) {
        float val = (logf(c + 1e-6f) - logZ[b]) * lmask[b * 5 + k];
        atomicAdd(out, val * (-1.0f / 512.0f));
    }
}

extern "C" void kernel_launch(void* const* d_in, const int* in_sizes, int n_in,
                              void* d_out, int out_size, void* d_ws, size_t ws_size,
                              hipStream_t stream)
{
    const int*   indices = (const int*)  d_in[0];
    const float* mask    = (const float*)d_in[1];
    const int*   labels  = (const int*)  d_in[2];
    const float* lmask   = (const float*)d_in[3];
    const float* emb     = (const float*)d_in[4];
    const float* ck      = (const float*)d_in[5];   // [512][32768]
    const float* omega   = (const float*)d_in[6];   // [2][4][128][32]
    const float* anchors = (const float*)d_in[7];   // [16][128]
    float* ws  = (float*)d_ws;
    float* out = (float*)d_out;
    int*   slot = (int*)(ws + OFF_SLOT);
    float* feat = ws + OFF_FEAT;

    hipMemsetAsync(ws + OFF_Z, 0, 4096 * sizeof(float), stream);
    hipMemsetAsync(slot, 0xFF, 32768 * sizeof(int), stream);   // -1
    hipMemsetAsync(out, 0, sizeof(float), stream);

    k_tr_anchors<<<1, 256, 0, stream>>>(anchors, ws + OFF_ANCT);
    k_scatter_slots<<<10, 256, 0, stream>>>(labels, slot);
    k_mean_embed<<<512, 256, 0, stream>>>(indices, mask, emb, ws + OFF_QUERY);
    k_query_feat<<<512, 256, 0, stream>>>(ws + OFF_QUERY, ws + OFF_ANCT, omega,
                                          ws + OFF_POLYQ, ws + OFF_PRFQ);
    k_labels<<<512, 256, 0, stream>>>(ck, ws + OFF_ANCT, omega, slot, feat, ws + OFF_Z);
    k_denom<<<128, 256, 0, stream>>>(ws + OFF_POLYQ, ws + OFF_PRFQ, ws + OFF_Z,
                                     ws + OFF_LOGZ);
    k_loss<<<40, 256, 0, stream>>>(labels, lmask, slot, feat,
                                   ws + OFF_POLYQ, ws + OFF_PRFQ, ws + OFF_LOGZ, out);
}